// Round 7
// baseline (77.110 us; speedup 1.0000x reference)
//
#include <hip/hip_runtime.h>

#define M_DIM 64
#define K_DIM 8192
#define N_DIM 8192
#define QB 32
#define NT 256                     // cols per block (64 per wave)
#define KC 32                      // k per stage == one quant block
#define SPLITS 16
#define KSPLIT (K_DIM / SPLITS)    // 512
#define NSTAGE (KSPLIT / KC)       // 16

typedef __attribute__((ext_vector_type(8))) short short8;     // MFMA A/B frag
typedef __attribute__((ext_vector_type(8))) unsigned short ushort8;
typedef __attribute__((ext_vector_type(4))) float f32x4;
typedef __attribute__((ext_vector_type(4))) int i32x4;

static_assert(NSTAGE * KC == KSPLIT, "tiling");

// f32 -> bf16 round-to-nearest-even
__device__ __forceinline__ unsigned short f2bf(float f) {
    unsigned u = __builtin_bit_cast(unsigned, f);
    u += 0x7fffu + ((u >> 16) & 1u);
    return (unsigned short)(u >> 16);
}

// Rewrites the whole output with bias every call (d_out poisoned once, never
// re-poisoned between replays; qgemm atomicAdds on top of this).
__global__ __launch_bounds__(256) void bias_init(const float* __restrict__ bias,
                                                 float* __restrict__ out) {
    int i = (blockIdx.x * 256 + threadIdx.x) * 4;
    *(f32x4*)(out + i) = *(const f32x4*)(bias + (i & (N_DIM - 1)));
}

// R7: 1KB-contiguous weight streaming (dwordx4 over a 256-col tile).
// Lane holds 4 consecutive cols x 8 rows -> LDS stays LINEAR [k][col]
// (b64 writes); B-frags built by strided u16 reads (4-way conflict, paid
// for by the DRAM-granularity win under test). x stays LDS-staged (R1
// lesson: direct-L2 A-frags caused the 80-115us regressions).
__global__ __launch_bounds__(256, 2) void qgemm(
    const float* __restrict__ x,       // [M][K]
    const float* __restrict__ scales,  // [K/QB][N]
    const float* __restrict__ zeros,   // [K/QB][N]
    const int*   __restrict__ qw,      // [K][N], 0..255
    float*       __restrict__ out)     // [M][N]
{
    // lw: [k 32][col 256] bf16, stride 260 shorts = 520B (8B-aligned rows;
    // 520/4 = 130 ≡ 2 mod 32 injects q into read banks -> 4-way max).
    // lx: [m 64][k 32] bf16, stride 40 shorts (R1 family).
    __shared__ unsigned short lw[2][KC][260];
    __shared__ unsigned short lx[2][M_DIM][40];

    const int tid  = threadIdx.x;
    const int lane = tid & 63;
    const int w    = tid >> 6;      // wave: owns cols [n0+64w, n0+64w+64)
    const int q    = lane >> 4;     // k-slot / C row-quarter
    const int lm   = lane & 15;

    const int n0 = blockIdx.x * NT;
    const int k0 = blockIdx.y * KSPLIT;

    // Lane's 4 consecutive weight columns; per wave-instr: 64 lanes x 16B
    // = 1KB contiguous (the experiment).
    const int*   qbase = qw     + (size_t)k0 * N_DIM        + n0 + 4 * lane;
    const float* sbase = scales + (size_t)(k0 >> 5) * N_DIM + n0 + 4 * lane;
    const float* zbase = zeros  + (size_t)(k0 >> 5) * N_DIM + n0 + 4 * lane;
    const float* xbase = x + (size_t)(tid >> 2) * K_DIM + k0 + (tid & 3) * 8;

    i32x4 qv[8];                    // 8 rows x 4 cols
    f32x4 sc, zc, xv0, xv1;

    auto load_stage = [&](int t) {
        const int* p = qbase + (size_t)t * KC * N_DIM;
        #pragma unroll
        for (int i = 0; i < 8; ++i)
            qv[i] = *(const i32x4*)(p + (size_t)(4 * i + w) * N_DIM);
        sc = *(const f32x4*)(sbase + (size_t)t * N_DIM);
        zc = *(const f32x4*)(zbase + (size_t)t * N_DIM);
        const float* xp = xbase + t * KC;
        xv0 = *(const f32x4*)xp;
        xv1 = *(const f32x4*)(xp + 4);
    };

    load_stage(0);

    f32x4 acc[4][4];                // [colfrag g][rowfrag rf]
    #pragma unroll
    for (int a = 0; a < 4; ++a)
        #pragma unroll
        for (int b = 0; b < 4; ++b) acc[a][b] = (f32x4){0.f, 0.f, 0.f, 0.f};

    for (int t = 0; t < NSTAGE; ++t) {
        const int cur = t & 1;

        // (1) dequant stage-t regs -> packed bf16 (frees qv)
        const f32x4 nz = -sc * zc;
        uint2 qd[8];
        #pragma unroll
        for (int i = 0; i < 8; ++i) {
            unsigned short h0 = f2bf(fmaf((float)qv[i][0], sc[0], nz[0]));
            unsigned short h1 = f2bf(fmaf((float)qv[i][1], sc[1], nz[1]));
            unsigned short h2 = f2bf(fmaf((float)qv[i][2], sc[2], nz[2]));
            unsigned short h3 = f2bf(fmaf((float)qv[i][3], sc[3], nz[3]));
            qd[i].x = (unsigned)h0 | ((unsigned)h1 << 16);
            qd[i].y = (unsigned)h2 | ((unsigned)h3 << 16);
        }
        ushort8 xw;
        #pragma unroll
        for (int e = 0; e < 4; ++e) {
            xw[e]     = f2bf(xv0[e]);
            xw[4 + e] = f2bf(xv1[e]);
        }

        // (2) prefetch stage t+1 (in flight until the barrier)
        if (t + 1 < NSTAGE) load_stage(t + 1);

        // (3) stage to LDS: linear [k][col] (lane's 4 cols = 8B contiguous)
        #pragma unroll
        for (int i = 0; i < 8; ++i)
            *(uint2*)&lw[cur][4 * i + w][4 * lane] = qd[i];
        *(ushort8*)&lx[cur][tid >> 2][(tid & 3) * 8] = xw;

        // (4) one barrier per stage
        __syncthreads();

        // (5) B-frags: col = n-local 64w+16g+lm, k = 8q..8q+7 (strided u16)
        short8 bf[4];
        #pragma unroll
        for (int g = 0; g < 4; ++g)
            #pragma unroll
            for (int j = 0; j < 8; ++j)
                bf[g][j] = (short)lw[cur][8 * q + j][64 * w + 16 * g + lm];

        // A-frags: row = 16rf+lm, k = 8q..8q+7 (b128)
        short8 af[4];
        #pragma unroll
        for (int rf = 0; rf < 4; ++rf)
            af[rf] = *(const short8*)&lx[cur][16 * rf + lm][8 * q];

        #pragma unroll
        for (int g = 0; g < 4; ++g)
            #pragma unroll
            for (int rf = 0; rf < 4; ++rf)
                acc[g][rf] = __builtin_amdgcn_mfma_f32_16x16x32_bf16(
                    af[rf], bf[g], acc[g][rf], 0, 0, 0);
    }

    // Epilogue: C layout col=lane&15, row=4*(lane>>4)+e (validated)
    #pragma unroll
    for (int g = 0; g < 4; ++g) {
        const int cn = n0 + 64 * w + 16 * g + lm;
        #pragma unroll
        for (int rf = 0; rf < 4; ++rf) {
            const int m = 16 * rf + 4 * q;
            #pragma unroll
            for (int e = 0; e < 4; ++e)
                atomicAdd(out + (size_t)(m + e) * N_DIM + cn, acc[g][rf][e]);
        }
    }
}

extern "C" void kernel_launch(void* const* d_in, const int* in_sizes, int n_in,
                              void* d_out, int out_size, void* d_ws, size_t ws_size,
                              hipStream_t stream) {
    const float* x      = (const float*)d_in[0];
    const float* scales = (const float*)d_in[1];
    const float* zeros  = (const float*)d_in[2];
    const float* bias   = (const float*)d_in[3];
    const int*   qw     = (const int*)d_in[4];
    float* out = (float*)d_out;

    bias_init<<<dim3((M_DIM * N_DIM) / 1024), 256, 0, stream>>>(bias, out);
    qgemm<<<dim3(N_DIM / NT, SPLITS), 256, 0, stream>>>(x, scales, zeros, qw, out);
}

// Round 8
// 67.940 us; speedup vs baseline: 1.1350x; 1.1350x over previous
//
#include <hip/hip_runtime.h>

#define M_DIM 64
#define K_DIM 8192
#define N_DIM 8192
#define QB 32
#define NT 64               // N columns per block
#define KC 64               // K per stage (2 quant blocks)
#define SPLITS 8
#define KSPLIT (K_DIM / SPLITS)    // 1024
#define NSTAGE (KSPLIT / KC)       // 16

typedef __attribute__((ext_vector_type(8))) short short8;     // 8 bf16 (4 VGPRs) - MFMA A/B frag
typedef __attribute__((ext_vector_type(8))) unsigned short ushort8;
typedef __attribute__((ext_vector_type(4))) float f32x4;

static_assert(NSTAGE * KC == KSPLIT, "split must tile");

// f32 -> bf16 round-to-nearest-even (no NaN inputs here)
__device__ __forceinline__ unsigned short f2bf(float f) {
    unsigned u = __builtin_bit_cast(unsigned, f);
    u += 0x7fffu + ((u >> 16) & 1u);
    return (unsigned short)(u >> 16);
}

// Rewrites the whole output with bias every call (d_out is poisoned once and
// never re-poisoned between replays; main kernel atomicAdds on top of this).
__global__ __launch_bounds__(256) void bias_init(const float* __restrict__ bias,
                                                 float* __restrict__ out) {
    int i = (blockIdx.x * 256 + threadIdx.x) * 4;
    int n = i & (N_DIM - 1);
    *(f32x4*)(out + i) = *(const f32x4*)(bias + n);
}

// R6 structure verbatim; ONE delta: __syncthreads() -> raw s_barrier with
// lgkmcnt(0) only. __syncthreads emits s_waitcnt vmcnt(0) before s_barrier,
// draining the stage-(t+1) weight prefetch at every barrier (convoy stall =
// the ~28% gap vs achievable BW). Raw barrier keeps vmem in flight; the
// compiler's automatic counted vmcnt before next iter's dequant waits ~one
// full stage after issue, so HBM latency is absorbed. LDS producer->consumer
// visibility preserved by the explicit lgkmcnt(0).
__global__ __launch_bounds__(256, 4) void qgemm(
    const float* __restrict__ x,       // [M][K]
    const float* __restrict__ scales,  // [K/QB][N]
    const float* __restrict__ zeros,   // [K/QB][N]
    const int*   __restrict__ qw,      // [K][N], values 0..255
    float*       __restrict__ out)     // [M][N]
{
    // Transposed weight tile [n][k] and x tile [m][k], bf16, double-buffered.
    // Row stride 72 elems = 144 B: multiple of 16 B (b128-aligned reads).
    __shared__ unsigned short lq[2][NT][72];
    __shared__ unsigned short lx[2][M_DIM][72];

    const int tid  = threadIdx.x;
    const int lane = tid & 63;
    const int w    = tid >> 6;          // wave 0..3, owns cols [16w,16w+16)

    const int n0 = blockIdx.x * NT;
    const int k0 = blockIdx.y * KSPLIT;

    const int qn   = n0 + lane;         // this thread's weight column
    const int xrow = tid >> 2;          // x staging: row 0..63
    const int xcol = (tid & 3) * 16;    // 16 k's per thread

    // stage registers
    int   qv[16];                       // 4 sets x 4 adjacent k, one column
    float sv0, sv1, zv0, zv1;
    f32x4 xv[4];

    auto load_stage = [&](int kk) {
        // weights: set s, elem j -> row kk+16s+4w+j, col qn.
        // Per wave per instr: 64 consecutive dwords (256B) -> fully coalesced.
        #pragma unroll
        for (int s = 0; s < 4; ++s)
            #pragma unroll
            for (int j = 0; j < 4; ++j)
                qv[s * 4 + j] = qw[(size_t)(kk + 16 * s + 4 * w + j) * N_DIM + qn];
        const int b0 = kk >> 5;
        sv0 = scales[(size_t)b0 * N_DIM + qn];
        sv1 = scales[(size_t)(b0 + 1) * N_DIM + qn];
        zv0 = zeros[(size_t)b0 * N_DIM + qn];
        zv1 = zeros[(size_t)(b0 + 1) * N_DIM + qn];
        #pragma unroll
        for (int i = 0; i < 4; ++i)
            xv[i] = *(const f32x4*)(x + (size_t)xrow * K_DIM + kk + xcol + 4 * i);
    };

    load_stage(k0);

    f32x4 acc[4];
    #pragma unroll
    for (int r = 0; r < 4; ++r) acc[r] = (f32x4){0.f, 0.f, 0.f, 0.f};

    for (int t = 0; t < NSTAGE; ++t) {
        const int cur = t & 1;

        // --- dequant stage-t regs -> packed bf16 ---
        const float nz0 = -sv0 * zv0, nz1 = -sv1 * zv1;
        const float s0r = sv0, s1r = sv1;
        uint2 qd[4];
        #pragma unroll
        for (int s = 0; s < 4; ++s) {
            const float sc = (s < 2) ? s0r : s1r;
            const float nz = (s < 2) ? nz0 : nz1;
            unsigned short h0 = f2bf(fmaf((float)qv[s * 4 + 0], sc, nz));
            unsigned short h1 = f2bf(fmaf((float)qv[s * 4 + 1], sc, nz));
            unsigned short h2 = f2bf(fmaf((float)qv[s * 4 + 2], sc, nz));
            unsigned short h3 = f2bf(fmaf((float)qv[s * 4 + 3], sc, nz));
            qd[s].x = (unsigned)h0 | ((unsigned)h1 << 16);
            qd[s].y = (unsigned)h2 | ((unsigned)h3 << 16);
        }
        ushort8 xw0, xw1;
        #pragma unroll
        for (int e = 0; e < 4; ++e) {
            xw0[e]     = f2bf(xv[0][e]);
            xw0[4 + e] = f2bf(xv[1][e]);
            xw1[e]     = f2bf(xv[2][e]);
            xw1[4 + e] = f2bf(xv[3][e]);
        }

        // --- issue loads for stage t+1 (stay in flight across the barrier) ---
        if (t + 1 < NSTAGE) load_stage(k0 + (t + 1) * KC);

        // --- stage to LDS (transposed [n][k] for B, [m][k] for A) ---
        #pragma unroll
        for (int s = 0; s < 4; ++s)
            *(uint2*)&lq[cur][lane][16 * s + 4 * w] = qd[s];
        *(ushort8*)&lx[cur][xrow][xcol]     = xw0;
        *(ushort8*)&lx[cur][xrow][xcol + 8] = xw1;

        // --- T4: raw barrier, NO vmcnt drain. lgkmcnt(0) makes this wave's
        // ds_writes visible; prefetch vmem stays outstanding. ---
        asm volatile("s_waitcnt lgkmcnt(0)" ::: "memory");
        __builtin_amdgcn_s_barrier();
        __builtin_amdgcn_sched_barrier(0);   // rule #18: no hoisting past barrier

        // --- MFMA: wave w = cols [16w,16w+16), all 64 rows, K step 32 ---
        #pragma unroll
        for (int c = 0; c < 2; ++c) {
            const short8 bf = *(const short8*)&lq[cur][16 * w + (lane & 15)]
                                                [32 * c + 8 * (lane >> 4)];
            #pragma unroll
            for (int r = 0; r < 4; ++r) {
                const short8 af = *(const short8*)&lx[cur][16 * r + (lane & 15)]
                                                    [32 * c + 8 * (lane >> 4)];
                acc[r] = __builtin_amdgcn_mfma_f32_16x16x32_bf16(af, bf, acc[r], 0, 0, 0);
            }
        }
    }

    // --- epilogue: C layout col=lane&15, row=4*(lane>>4)+e (verified) ---
    const int cn = n0 + 16 * w + (lane & 15);
    #pragma unroll
    for (int r = 0; r < 4; ++r) {
        const int m = 16 * r + 4 * (lane >> 4);
        #pragma unroll
        for (int e = 0; e < 4; ++e)
            atomicAdd(out + (size_t)(m + e) * N_DIM + cn, acc[r][e]);
    }
}

extern "C" void kernel_launch(void* const* d_in, const int* in_sizes, int n_in,
                              void* d_out, int out_size, void* d_ws, size_t ws_size,
                              hipStream_t stream) {
    const float* x      = (const float*)d_in[0];
    const float* scales = (const float*)d_in[1];
    const float* zeros  = (const float*)d_in[2];
    const float* bias   = (const float*)d_in[3];
    const int*   qw     = (const int*)d_in[4];
    float* out = (float*)d_out;

    bias_init<<<dim3((M_DIM * N_DIM) / 1024), 256, 0, stream>>>(bias, out);
    qgemm<<<dim3(N_DIM / NT, SPLITS), 256, 0, stream>>>(x, scales, zeros, qw, out);
}

// Round 9
// 59.907 us; speedup vs baseline: 1.2872x; 1.1341x over previous
//
#include <hip/hip_runtime.h>

#define M_DIM 64
#define K_DIM 8192
#define N_DIM 8192
#define QB 32
#define NT 64               // N columns per block
#define KC 64               // K per stage (2 quant blocks)
#define SPLITS 4
#define KSPLIT (K_DIM / SPLITS)    // 2048
#define NSTAGE (KSPLIT / KC)       // 32 (even, required by ping-pong unroll)

typedef __attribute__((ext_vector_type(8))) short short8;     // MFMA A/B frag
typedef __attribute__((ext_vector_type(8))) unsigned short ushort8;
typedef __attribute__((ext_vector_type(4))) float f32x4;
typedef __attribute__((ext_vector_type(4))) unsigned int u32x4;

static_assert(NSTAGE % 2 == 0 && NSTAGE * KC == KSPLIT, "tiling");

// f32 -> bf16 round-to-nearest-even
__device__ __forceinline__ unsigned short f2bf(float f) {
    unsigned u = __builtin_bit_cast(unsigned, f);
    u += 0x7fffu + ((u >> 16) & 1u);
    return (unsigned short)(u >> 16);
}

// Rewrites the whole output with bias every call (clears the 0xAA poison;
// qgemm atomicAdds on top of this).
__global__ __launch_bounds__(256) void bias_init(const float* __restrict__ bias,
                                                 float* __restrict__ out) {
    int i = (blockIdx.x * 256 + threadIdx.x) * 4;
    *(f32x4*)(out + i) = *(const f32x4*)(bias + (i & (N_DIM - 1)));
}

// One-shot x f32 -> bf16 into workspace (1 MB, L2-resident). Removes the
// per-stage, per-block-duplicated x conversion VALU from the hot loop.
__global__ __launch_bounds__(256) void xcvt(const float* __restrict__ x,
                                            unsigned short* __restrict__ xb) {
    int i = (blockIdx.x * 256 + threadIdx.x) * 8;
    f32x4 a = *(const f32x4*)(x + i);
    f32x4 b = *(const f32x4*)(x + i + 4);
    ushort8 o;
    #pragma unroll
    for (int e = 0; e < 4; ++e) { o[e] = f2bf(a[e]); o[4 + e] = f2bf(b[e]); }
    *(ushort8*)(xb + i) = o;
}

// R1 structure (60.2us validated: LDS-staged x + weights, one __syncthreads
// per stage, double-buffer, atomic epilogue). Deltas:
//  1. Ping-pong stage registers; prefetch for stage t+1 issues at the TOP of
//     stage t (before dequant), ~700cy earlier than R1 -> the barrier's
//     vmcnt(0) drain has far less residual HBM latency to eat.
//  2. x staged from precomputed bf16 xb (2 loads + 2 LDS stores, no VALU).
template <bool XBF>
__global__ __launch_bounds__(256, 2) void qgemm(
    const float* __restrict__ x,             // [M][K] f32 (fallback)
    const unsigned short* __restrict__ xb,   // [M][K] bf16 (main)
    const float* __restrict__ scales,        // [K/QB][N]
    const float* __restrict__ zeros,         // [K/QB][N]
    const int*   __restrict__ qw,            // [K][N], 0..255
    float*       __restrict__ out)           // [M][N]
{
    // Transposed weight tile [n][k] and x tile [m][k], bf16, double-buffered.
    // Row stride 72 shorts = 144 B (16B-aligned b128 reads). R1-validated.
    __shared__ unsigned short lq[2][NT][72];
    __shared__ unsigned short lx[2][M_DIM][72];

    const int tid  = threadIdx.x;
    const int lane = tid & 63;
    const int w    = tid >> 6;          // wave 0..3, owns cols [16w,16w+16)

    const int n0 = blockIdx.x * NT;
    const int k0 = blockIdx.y * KSPLIT;

    const int qn   = n0 + lane;         // this thread's weight column
    const int xrow = tid >> 2;          // x staging: row 0..63
    const int xcol = (tid & 3) * 16;    // 16 k's per thread

    const int*   qp = qw     + (size_t)k0 * N_DIM + qn;
    const float* sp = scales + (size_t)(k0 >> 5) * N_DIM + qn;
    const float* zp = zeros  + (size_t)(k0 >> 5) * N_DIM + qn;

    // ping-pong stage registers
    int   qvA[16], qvB[16];
    float svA0, svA1, zvA0, zvA1, svB0, svB1, zvB0, zvB1;
    u32x4 xvA[2], xvB[2];               // XBF: 16 bf16 per thread
    f32x4 xfA[4], xfB[4];               // fallback: 16 f32 per thread

#define LOADS(QV, S0, S1, Z0, Z1, XV, XF, T)                                  \
    do {                                                                      \
        const int* _p = qp + (size_t)(T) * KC * N_DIM;                        \
        _Pragma("unroll")                                                     \
        for (int s = 0; s < 4; ++s)                                           \
            _Pragma("unroll")                                                 \
            for (int j = 0; j < 4; ++j)                                       \
                QV[4 * s + j] = _p[(size_t)(16 * s + 4 * w + j) * N_DIM];     \
        S0 = sp[(size_t)(2 * (T)) * N_DIM];                                   \
        S1 = sp[(size_t)(2 * (T) + 1) * N_DIM];                               \
        Z0 = zp[(size_t)(2 * (T)) * N_DIM];                                   \
        Z1 = zp[(size_t)(2 * (T) + 1) * N_DIM];                               \
        if (XBF) {                                                            \
            const unsigned short* _xp =                                       \
                xb + (size_t)xrow * K_DIM + (k0 + (T) * KC) + xcol;           \
            XV[0] = *(const u32x4*)_xp;                                       \
            XV[1] = *(const u32x4*)(_xp + 8);                                 \
        } else {                                                              \
            const float* _xp =                                                \
                x + (size_t)xrow * K_DIM + (k0 + (T) * KC) + xcol;            \
            _Pragma("unroll")                                                 \
            for (int i = 0; i < 4; ++i) XF[i] = *(const f32x4*)(_xp + 4 * i); \
        }                                                                     \
    } while (0)

#define BODY(QV, S0, S1, Z0, Z1, XV, XF, CUR)                                 \
    do {                                                                      \
        const float _nz0 = -(S0) * (Z0), _nz1 = -(S1) * (Z1);                 \
        uint2 qd[4];                                                          \
        _Pragma("unroll")                                                     \
        for (int s = 0; s < 4; ++s) {                                         \
            const float _sc = (s < 2) ? (S0) : (S1);                          \
            const float _nz = (s < 2) ? _nz0 : _nz1;                          \
            unsigned short h0 = f2bf(fmaf((float)QV[4 * s + 0], _sc, _nz));   \
            unsigned short h1 = f2bf(fmaf((float)QV[4 * s + 1], _sc, _nz));   \
            unsigned short h2 = f2bf(fmaf((float)QV[4 * s + 2], _sc, _nz));   \
            unsigned short h3 = f2bf(fmaf((float)QV[4 * s + 3], _sc, _nz));   \
            qd[s].x = (unsigned)h0 | ((unsigned)h1 << 16);                    \
            qd[s].y = (unsigned)h2 | ((unsigned)h3 << 16);                    \
        }                                                                     \
        _Pragma("unroll")                                                     \
        for (int s = 0; s < 4; ++s)                                           \
            *(uint2*)&lq[CUR][lane][16 * s + 4 * w] = qd[s];                  \
        if (XBF) {                                                            \
            *(u32x4*)&lx[CUR][xrow][xcol]     = XV[0];                        \
            *(u32x4*)&lx[CUR][xrow][xcol + 8] = XV[1];                        \
        } else {                                                              \
            ushort8 xw0, xw1;                                                 \
            _Pragma("unroll")                                                 \
            for (int e = 0; e < 4; ++e) {                                     \
                xw0[e]     = f2bf(XF[0][e]);                                  \
                xw0[4 + e] = f2bf(XF[1][e]);                                  \
                xw1[e]     = f2bf(XF[2][e]);                                  \
                xw1[4 + e] = f2bf(XF[3][e]);                                  \
            }                                                                 \
            *(ushort8*)&lx[CUR][xrow][xcol]     = xw0;                        \
            *(ushort8*)&lx[CUR][xrow][xcol + 8] = xw1;                        \
        }                                                                     \
    } while (0)

#define MM(CUR)                                                               \
    do {                                                                      \
        _Pragma("unroll")                                                     \
        for (int c = 0; c < 2; ++c) {                                         \
            const short8 bf = *(const short8*)&lq[CUR][16 * w + (lane & 15)]  \
                                                 [32 * c + 8 * (lane >> 4)];  \
            _Pragma("unroll")                                                 \
            for (int r = 0; r < 4; ++r) {                                     \
                const short8 af = *(const short8*)&lx[CUR][16 * r + (lane & 15)] \
                                                     [32 * c + 8 * (lane >> 4)]; \
                acc[r] = __builtin_amdgcn_mfma_f32_16x16x32_bf16(af, bf, acc[r], 0, 0, 0); \
            }                                                                 \
        }                                                                     \
    } while (0)

    f32x4 acc[4];
    #pragma unroll
    for (int r = 0; r < 4; ++r) acc[r] = (f32x4){0.f, 0.f, 0.f, 0.f};

    LOADS(qvA, svA0, svA1, zvA0, zvA1, xvA, xfA, 0);

    for (int t = 0; t < NSTAGE; t += 2) {
        // issue t+1 loads FIRST (ping-pong B set; no WAR with A dequant)
        LOADS(qvB, svB0, svB1, zvB0, zvB1, xvB, xfB, t + 1);
        BODY(qvA, svA0, svA1, zvA0, zvA1, xvA, xfA, 0);
        __syncthreads();
        MM(0);
        if (t + 2 < NSTAGE)
            LOADS(qvA, svA0, svA1, zvA0, zvA1, xvA, xfA, t + 2);
        BODY(qvB, svB0, svB1, zvB0, zvB1, xvB, xfB, 1);
        __syncthreads();
        MM(1);
    }

#undef LOADS
#undef BODY
#undef MM

    // epilogue: C layout col=lane&15, row=4*(lane>>4)+e (validated)
    const int cn = n0 + 16 * w + (lane & 15);
    #pragma unroll
    for (int r = 0; r < 4; ++r) {
        const int m = 16 * r + 4 * (lane >> 4);
        #pragma unroll
        for (int e = 0; e < 4; ++e)
            atomicAdd(out + (size_t)(m + e) * N_DIM + cn, acc[r][e]);
    }
}

extern "C" void kernel_launch(void* const* d_in, const int* in_sizes, int n_in,
                              void* d_out, int out_size, void* d_ws, size_t ws_size,
                              hipStream_t stream) {
    const float* x      = (const float*)d_in[0];
    const float* scales = (const float*)d_in[1];
    const float* zeros  = (const float*)d_in[2];
    const float* bias   = (const float*)d_in[3];
    const int*   qw     = (const int*)d_in[4];
    float* out = (float*)d_out;
    unsigned short* xbf = (unsigned short*)d_ws;

    const bool use_xbf = ws_size >= (size_t)M_DIM * K_DIM * 2;

    bias_init<<<dim3((M_DIM * N_DIM) / 1024), 256, 0, stream>>>(bias, out);
    if (use_xbf) {
        xcvt<<<dim3((M_DIM * K_DIM) / 2048), 256, 0, stream>>>(x, xbf);
        qgemm<true><<<dim3(N_DIM / NT, SPLITS), 256, 0, stream>>>(
            x, xbf, scales, zeros, qw, out);
    } else {
        qgemm<false><<<dim3(N_DIM / NT, SPLITS), 256, 0, stream>>>(
            x, nullptr, scales, zeros, qw, out);
    }
}